// Round 2
// baseline (1922.375 us; speedup 1.0000x reference)
//
#include <hip/hip_runtime.h>
#include <math.h>

#define R_ROUTES 1152
#define CIN 8
#define COUT 16
#define BATCH 512
#define NCAPS 10
#define NUM_ROUNDS 3

// One workgroup per (n, b). Priors live in REGISTERS of owning threads:
// thread t owns rows r = t + 256k (5 rows if t<128 else 4) -> pr[5][16].
// LDS only holds small reduction scratch (~18.5 KB) -> occupancy is
// VGPR-bound: __launch_bounds__(256,4) caps at 128 VGPR = 16 waves/CU.
extern "C" __global__ void __launch_bounds__(256, 4)
capsule_routing_reg(const float* __restrict__ x,
                    const float* __restrict__ W,
                    float* __restrict__ out)
{
    __shared__ float scratch[256 * 17];  // 17408 B, stride 17 breaks conflicts
    __shared__ float part[256];          // stage-1 partials, [g*16+o]
    __shared__ float sred[4];            // per-wave exp-sum partials
    __shared__ float sv[16];             // s vector

    const int blk = blockIdx.x;          // n-major: W[n] stays L2-resident
    const int n = blk >> 9;
    const int b = blk & 511;
    const int t = threadIdx.x;

    const float* __restrict__ xb = x + (size_t)b * (R_ROUTES * CIN);
    const float* __restrict__ Wn = W + (size_t)n * (R_ROUTES * CIN * COUT);

    const int nr = (t < 128) ? 5 : 4;    // wave-uniform (waves 0,1 vs 2,3)

    // ---------------- Phase A: priors for owned rows, into registers.
    float pr[5][16];
    #pragma unroll
    for (int k = 0; k < 5; ++k) {
        #pragma unroll
        for (int o = 0; o < 16; ++o) pr[k][o] = 0.f;
        if (k < nr) {
            const int r = t + (k << 8);
            const float4 xv0 = *(const float4*)(xb + r * CIN);
            const float4 xv1 = *(const float4*)(xb + r * CIN + 4);
            const float xs[8] = {xv0.x, xv0.y, xv0.z, xv0.w,
                                 xv1.x, xv1.y, xv1.z, xv1.w};
            const float4* __restrict__ wp = (const float4*)(Wn + (size_t)r * (CIN * COUT));
            #pragma unroll
            for (int i = 0; i < 8; ++i) {
                const float4 w0 = wp[i * 4 + 0];   // one 64B line per i
                const float4 w1 = wp[i * 4 + 1];
                const float4 w2 = wp[i * 4 + 2];
                const float4 w3 = wp[i * 4 + 3];
                const float xi = xs[i];
                pr[k][0]  = fmaf(xi, w0.x, pr[k][0]);
                pr[k][1]  = fmaf(xi, w0.y, pr[k][1]);
                pr[k][2]  = fmaf(xi, w0.z, pr[k][2]);
                pr[k][3]  = fmaf(xi, w0.w, pr[k][3]);
                pr[k][4]  = fmaf(xi, w1.x, pr[k][4]);
                pr[k][5]  = fmaf(xi, w1.y, pr[k][5]);
                pr[k][6]  = fmaf(xi, w1.z, pr[k][6]);
                pr[k][7]  = fmaf(xi, w1.w, pr[k][7]);
                pr[k][8]  = fmaf(xi, w2.x, pr[k][8]);
                pr[k][9]  = fmaf(xi, w2.y, pr[k][9]);
                pr[k][10] = fmaf(xi, w2.z, pr[k][10]);
                pr[k][11] = fmaf(xi, w2.w, pr[k][11]);
                pr[k][12] = fmaf(xi, w3.x, pr[k][12]);
                pr[k][13] = fmaf(xi, w3.y, pr[k][13]);
                pr[k][14] = fmaf(xi, w3.z, pr[k][14]);
                pr[k][15] = fmaf(xi, w3.w, pr[k][15]);
            }
        }
    }

    // ---------------- Phase B: 3 routing rounds.
    // Logits bounded (|dot(p,v)| <~ 15 per round) -> exp without max-shift is
    // safe in fp32; softmax result identical up to rounding.
    float bl[5] = {0.f, 0.f, 0.f, 0.f, 0.f};

    for (int round = 0; round < NUM_ROUNDS; ++round) {
        float e[5];
        if (round == 0) {
            // softmax(0) = uniform
            e[0] = e[1] = e[2] = e[3] = 1.f;
            e[4] = (nr == 5) ? 1.f : 0.f;
        } else {
            #pragma unroll
            for (int k = 0; k < 5; ++k)
                e[k] = (k < nr) ? __expf(bl[k]) : 0.f;
            // block-sum of weights: wave butterfly + cross-wave LDS
            float es = e[0] + e[1] + e[2] + e[3] + e[4];
            #pragma unroll
            for (int off = 32; off > 0; off >>= 1) es += __shfl_xor(es, off, 64);
            if ((t & 63) == 0) sred[t >> 6] = es;
        }

        // local weighted sum over owned rows (all-register)
        float acc[16];
        #pragma unroll
        for (int o = 0; o < 16; ++o) {
            float a = e[0] * pr[0][o];
            a = fmaf(e[1], pr[1][o], a);
            a = fmaf(e[2], pr[2][o], a);
            a = fmaf(e[3], pr[3][o], a);
            a = fmaf(e[4], pr[4][o], a);
            acc[o] = a;
        }
        #pragma unroll
        for (int o = 0; o < 16; ++o) scratch[t * 17 + o] = acc[o];
        __syncthreads();                                   // bar1

        // stage 1: 256 threads as (o = t&15, g = t>>4), sum 16 rows each
        {
            const int o = t & 15, g = t >> 4;
            float p1 = 0.f;
            #pragma unroll
            for (int j = 0; j < 16; ++j)
                p1 += scratch[(g + (j << 4)) * 17 + o];
            part[(g << 4) + o] = p1;
        }
        __syncthreads();                                   // bar2

        // stage 2: 16 threads finish s_o
        if (t < 16) {
            float s = 0.f;
            #pragma unroll
            for (int g2 = 0; g2 < 16; ++g2) s += part[(g2 << 4) + t];
            const float Z = (round == 0)
                ? (float)R_ROUTES
                : (sred[0] + sred[1] + sred[2] + sred[3]);
            sv[t] = s / Z;
        }
        __syncthreads();                                   // bar3

        // squash factor, computed redundantly from LDS broadcasts
        float svr[16];
        float sn = 0.f;
        #pragma unroll
        for (int o = 0; o < 16; ++o) { svr[o] = sv[o]; sn = fmaf(svr[o], svr[o], sn); }
        const float factor = sn / ((1.0f + sn) * sqrtf(sn));

        if (round == NUM_ROUNDS - 1) {
            if (t < 16) out[(size_t)blk * COUT + t] = factor * svr[t];
        } else {
            // logit update: fully register-local per owned row
            #pragma unroll
            for (int k = 0; k < 5; ++k) {
                float d = 0.f;
                #pragma unroll
                for (int o = 0; o < 16; ++o) d = fmaf(pr[k][o], svr[o], d);
                bl[k] = fmaf(factor, d, bl[k]);   // invalid rows: pr==0 -> d==0
            }
            // no barrier needed: next round's LDS writes are all after bar1
        }
    }
}

extern "C" void kernel_launch(void* const* d_in, const int* in_sizes, int n_in,
                              void* d_out, int out_size, void* d_ws, size_t ws_size,
                              hipStream_t stream) {
    const float* x = (const float*)d_in[0];   // [512, 1152, 8] fp32
    const float* W = (const float*)d_in[1];   // [10, 1152, 8, 16] fp32
    float* out = (float*)d_out;               // [10, 512, 1, 1, 16] fp32

    dim3 grid(NCAPS * BATCH);                 // 5120 blocks, n-major
    dim3 block(256);
    capsule_routing_reg<<<grid, block, 0, stream>>>(x, W, out);
}

// Round 3
// 1184.540 us; speedup vs baseline: 1.6229x; 1.6229x over previous
//
#include <hip/hip_runtime.h>
#include <math.h>

#define R_ROUTES 1152
#define CIN 8
#define COUT 16
#define BATCH 512
#define NCAPS 10
#define NUM_ROUNDS 3

// One workgroup (512 threads) per (n, b). Thread t owns rows r = t + 512k:
// 3 rows for t<128 (waves 0-1), 2 rows for t>=128 (waves 2-7) -> pr[3][16] =
// 48 VGPRs. __launch_bounds__(512,4) caps VGPRs at 128 -> 2 blocks/CU =
// 16 waves/CU. LDS: 512*20-word scratch (b128-aligned, bank-optimal) ~43 KB.
extern "C" __global__ void __launch_bounds__(512, 4)
capsule_routing_r3(const float* __restrict__ x,
                   const float* __restrict__ W,
                   float* __restrict__ out)
{
    __shared__ float scratch[512 * 20];  // 40960 B
    __shared__ float part[512];          // stage-1 partials [(g<<4)+o]
    __shared__ float sred[8];            // per-wave exp-sum partials
    __shared__ float sv[16];             // s vector

    const int blk = blockIdx.x;          // n-major: W[n] stays L2-resident
    const int n = blk >> 9;
    const int b = blk & 511;
    const int t = threadIdx.x;

    const float* __restrict__ xb = x + (size_t)b * (R_ROUTES * CIN);
    const float* __restrict__ Wn = W + (size_t)n * (R_ROUTES * CIN * COUT);

    const int nr = (t < 128) ? 3 : 2;    // wave-uniform

    // ---------------- Phase A: priors for owned rows -> registers
    float pr[3][16];
    #pragma unroll
    for (int k = 0; k < 3; ++k) {
        #pragma unroll
        for (int o = 0; o < 16; ++o) pr[k][o] = 0.f;
        if (k < nr) {
            const int r = t + (k << 9);
            const float4 xv0 = *(const float4*)(xb + r * CIN);
            const float4 xv1 = *(const float4*)(xb + r * CIN + 4);
            const float xs[8] = {xv0.x, xv0.y, xv0.z, xv0.w,
                                 xv1.x, xv1.y, xv1.z, xv1.w};
            const float4* __restrict__ wp = (const float4*)(Wn + (size_t)r * (CIN * COUT));
            #pragma unroll
            for (int i = 0; i < 8; ++i) {
                const float4 w0 = wp[i * 4 + 0];
                const float4 w1 = wp[i * 4 + 1];
                const float4 w2 = wp[i * 4 + 2];
                const float4 w3 = wp[i * 4 + 3];
                const float xi = xs[i];
                pr[k][0]  = fmaf(xi, w0.x, pr[k][0]);
                pr[k][1]  = fmaf(xi, w0.y, pr[k][1]);
                pr[k][2]  = fmaf(xi, w0.z, pr[k][2]);
                pr[k][3]  = fmaf(xi, w0.w, pr[k][3]);
                pr[k][4]  = fmaf(xi, w1.x, pr[k][4]);
                pr[k][5]  = fmaf(xi, w1.y, pr[k][5]);
                pr[k][6]  = fmaf(xi, w1.z, pr[k][6]);
                pr[k][7]  = fmaf(xi, w1.w, pr[k][7]);
                pr[k][8]  = fmaf(xi, w2.x, pr[k][8]);
                pr[k][9]  = fmaf(xi, w2.y, pr[k][9]);
                pr[k][10] = fmaf(xi, w2.z, pr[k][10]);
                pr[k][11] = fmaf(xi, w2.w, pr[k][11]);
                pr[k][12] = fmaf(xi, w3.x, pr[k][12]);
                pr[k][13] = fmaf(xi, w3.y, pr[k][13]);
                pr[k][14] = fmaf(xi, w3.z, pr[k][14]);
                pr[k][15] = fmaf(xi, w3.w, pr[k][15]);
            }
        }
    }

    // ---------------- Phase B: 3 routing rounds (logits bounded, no max-shift)
    float bl[3] = {0.f, 0.f, 0.f};

    for (int round = 0; round < NUM_ROUNDS; ++round) {
        float e[3];
        if (round == 0) {
            e[0] = e[1] = 1.f;
            e[2] = (nr == 3) ? 1.f : 0.f;
        } else {
            e[0] = __expf(bl[0]);
            e[1] = __expf(bl[1]);
            e[2] = (nr == 3) ? __expf(bl[2]) : 0.f;
            float es = e[0] + e[1] + e[2];
            #pragma unroll
            for (int off = 32; off > 0; off >>= 1) es += __shfl_xor(es, off, 64);
            if ((t & 63) == 0) sred[t >> 6] = es;
        }

        // local weighted sum over owned rows (registers only)
        #pragma unroll
        for (int o = 0; o < 16; o += 4) {
            float4 a;
            a.x = fmaf(e[2], pr[2][o+0], fmaf(e[1], pr[1][o+0], e[0] * pr[0][o+0]));
            a.y = fmaf(e[2], pr[2][o+1], fmaf(e[1], pr[1][o+1], e[0] * pr[0][o+1]));
            a.z = fmaf(e[2], pr[2][o+2], fmaf(e[1], pr[1][o+2], e[0] * pr[0][o+2]));
            a.w = fmaf(e[2], pr[2][o+3], fmaf(e[1], pr[1][o+3], e[0] * pr[0][o+3]));
            *(float4*)(scratch + t * 20 + o) = a;   // 20-word stride: aligned + bank-optimal
        }
        __syncthreads();                                   // bar1

        // stage 1: (o = t&15, g = t>>4 in 0..31), each sums 16 source threads
        {
            const int o = t & 15, g = t >> 4;
            float p1 = 0.f;
            #pragma unroll
            for (int j = 0; j < 16; ++j)
                p1 += scratch[(g + (j << 5)) * 20 + o];
            part[(g << 4) + o] = p1;
        }
        __syncthreads();                                   // bar2

        // stage 2: 16 threads finish s_o
        if (t < 16) {
            float s = 0.f;
            #pragma unroll
            for (int g2 = 0; g2 < 32; ++g2) s += part[(g2 << 4) + t];
            float Z;
            if (round == 0) {
                Z = (float)R_ROUTES;
            } else {
                Z = sred[0] + sred[1] + sred[2] + sred[3]
                  + sred[4] + sred[5] + sred[6] + sred[7];
            }
            sv[t] = s / Z;
        }
        __syncthreads();                                   // bar3

        // squash factor from LDS broadcasts
        float svr[16];
        float sn = 0.f;
        #pragma unroll
        for (int o = 0; o < 16; ++o) { svr[o] = sv[o]; sn = fmaf(svr[o], svr[o], sn); }
        const float factor = sn / ((1.0f + sn) * sqrtf(sn));

        if (round == NUM_ROUNDS - 1) {
            if (t < 16) out[(size_t)blk * COUT + t] = factor * svr[t];
        } else {
            // logit update: register-local per owned row (pr==0 for invalid)
            #pragma unroll
            for (int k = 0; k < 3; ++k) {
                float d = 0.f;
                #pragma unroll
                for (int o = 0; o < 16; ++o) d = fmaf(pr[k][o], svr[o], d);
                bl[k] = fmaf(factor, d, bl[k]);
            }
            // no barrier needed: next round's LDS writes occur before bar1
        }
    }
}

extern "C" void kernel_launch(void* const* d_in, const int* in_sizes, int n_in,
                              void* d_out, int out_size, void* d_ws, size_t ws_size,
                              hipStream_t stream) {
    const float* x = (const float*)d_in[0];   // [512, 1152, 8] fp32
    const float* W = (const float*)d_in[1];   // [10, 1152, 8, 16] fp32
    float* out = (float*)d_out;               // [10, 512, 1, 1, 16] fp32

    dim3 grid(NCAPS * BATCH);                 // 5120 blocks, n-major
    dim3 block(512);
    capsule_routing_r3<<<grid, block, 0, stream>>>(x, W, out);
}

// Round 4
// 557.157 us; speedup vs baseline: 3.4503x; 2.1260x over previous
//
#include <hip/hip_runtime.h>
#include <math.h>

#define R_ROUTES 1152
#define CIN 8
#define COUT 16
#define BATCH 512
#define NCAPS 10
#define NUM_ROUNDS 3

// Manual round-to-nearest-even f32 -> bf16 (deterministic, order-explicit).
__device__ __forceinline__ unsigned int bf16_rne(float f) {
    unsigned int u = __float_as_uint(f);
    u += 0x7fffu + ((u >> 16) & 1u);
    return u >> 16;
}
__device__ __forceinline__ unsigned int pack2(float lo, float hi) {
    return bf16_rne(lo) | (bf16_rne(hi) << 16);
}
__device__ __forceinline__ float bf_lo(unsigned int u) { return __uint_as_float(u << 16); }
__device__ __forceinline__ float bf_hi(unsigned int u) { return __uint_as_float(u & 0xffff0000u); }

// One workgroup (512 threads) per (n, b). Thread t OWNS rows r = t + 512k
// (3 rows if t<128, else 2). Priors are bf16-packed in LDS, owner-local:
// row r at pbuf[r*8 .. r*8+7] (32 B) -> 2x ds_read/write_b128, no cross-
// thread access, no barrier needed for pbuf. Cross-thread LDS is only the
// small reduction scratch. Total LDS ~47 KB -> 2-3 blocks/CU.
extern "C" __global__ void __launch_bounds__(512, 4)
capsule_routing_bf(const float* __restrict__ x,
                   const float* __restrict__ W,
                   float* __restrict__ out)
{
    __shared__ unsigned int pbuf[R_ROUTES * 8];   // 36864 B: bf16 priors
    __shared__ float red[128 * 20];               // 10240 B: writer w at red+w*20 (16B-aligned)
    __shared__ float part[256];                   // 1024 B
    __shared__ float sred[8];                     // per-wave exp sums
    __shared__ float sv[16];                      // s vector

    const int blk = blockIdx.x;                   // n-major: W[n] stays L2-resident
    const int n = blk >> 9;
    const int b = blk & 511;
    const int t = threadIdx.x;
    const int nr = (t < 128) ? 3 : 2;             // wave-uniform

    const float* __restrict__ xb = x + (size_t)b * (R_ROUTES * CIN);
    const float* __restrict__ Wn = W + (size_t)n * (R_ROUTES * CIN * COUT);

    // ---------------- Phase A: priors for owned rows -> bf16 LDS
    #pragma unroll
    for (int k = 0; k < 3; ++k) {
        if (k < nr) {
            const int r = t + (k << 9);
            const float4 xv0 = *(const float4*)(xb + r * CIN);
            const float4 xv1 = *(const float4*)(xb + r * CIN + 4);
            const float xs[8] = {xv0.x, xv0.y, xv0.z, xv0.w,
                                 xv1.x, xv1.y, xv1.z, xv1.w};
            float row[16];
            #pragma unroll
            for (int o = 0; o < 16; ++o) row[o] = 0.f;
            const float4* __restrict__ wp = (const float4*)(Wn + (size_t)r * (CIN * COUT));
            #pragma unroll
            for (int i = 0; i < 8; ++i) {
                const float4 w0 = wp[i * 4 + 0];
                const float4 w1 = wp[i * 4 + 1];
                const float4 w2 = wp[i * 4 + 2];
                const float4 w3 = wp[i * 4 + 3];
                const float xi = xs[i];
                row[0]  = fmaf(xi, w0.x, row[0]);
                row[1]  = fmaf(xi, w0.y, row[1]);
                row[2]  = fmaf(xi, w0.z, row[2]);
                row[3]  = fmaf(xi, w0.w, row[3]);
                row[4]  = fmaf(xi, w1.x, row[4]);
                row[5]  = fmaf(xi, w1.y, row[5]);
                row[6]  = fmaf(xi, w1.z, row[6]);
                row[7]  = fmaf(xi, w1.w, row[7]);
                row[8]  = fmaf(xi, w2.x, row[8]);
                row[9]  = fmaf(xi, w2.y, row[9]);
                row[10] = fmaf(xi, w2.z, row[10]);
                row[11] = fmaf(xi, w2.w, row[11]);
                row[12] = fmaf(xi, w3.x, row[12]);
                row[13] = fmaf(xi, w3.y, row[13]);
                row[14] = fmaf(xi, w3.z, row[14]);
                row[15] = fmaf(xi, w3.w, row[15]);
            }
            uint4 u0, u1;
            u0.x = pack2(row[0],  row[1]);
            u0.y = pack2(row[2],  row[3]);
            u0.z = pack2(row[4],  row[5]);
            u0.w = pack2(row[6],  row[7]);
            u1.x = pack2(row[8],  row[9]);
            u1.y = pack2(row[10], row[11]);
            u1.z = pack2(row[12], row[13]);
            u1.w = pack2(row[14], row[15]);
            *(uint4*)(pbuf + r * 8)     = u0;
            *(uint4*)(pbuf + r * 8 + 4) = u1;
        }
    }
    // No barrier: pbuf rows are owner-private.

    // ---------------- Phase B: 3 routing rounds
    float bl0 = 0.f, bl1 = 0.f, bl2 = 0.f;

    for (int round = 0; round < NUM_ROUNDS; ++round) {
        float e0, e1, e2;
        if (round == 0) {
            e0 = 1.f; e1 = 1.f; e2 = (nr == 3) ? 1.f : 0.f;
        } else {
            e0 = __expf(bl0);
            e1 = __expf(bl1);
            e2 = (nr == 3) ? __expf(bl2) : 0.f;
            float es = e0 + e1 + e2;
            #pragma unroll
            for (int off = 32; off > 0; off >>= 1) es += __shfl_xor(es, off, 64);
            if ((t & 63) == 0) sred[t >> 6] = es;   // read at stage-3 (after bar2)
        }

        // Owner-local weighted sum -> acc[16]
        float acc[16];
        #pragma unroll
        for (int o = 0; o < 16; ++o) acc[o] = 0.f;
        #pragma unroll
        for (int k = 0; k < 3; ++k) {
            if (k < nr) {
                const int r = t + (k << 9);
                const uint4 a = *(const uint4*)(pbuf + r * 8);
                const uint4 c = *(const uint4*)(pbuf + r * 8 + 4);
                const float w = (k == 0) ? e0 : ((k == 1) ? e1 : e2);
                acc[0]  = fmaf(w, bf_lo(a.x), acc[0]);
                acc[1]  = fmaf(w, bf_hi(a.x), acc[1]);
                acc[2]  = fmaf(w, bf_lo(a.y), acc[2]);
                acc[3]  = fmaf(w, bf_hi(a.y), acc[3]);
                acc[4]  = fmaf(w, bf_lo(a.z), acc[4]);
                acc[5]  = fmaf(w, bf_hi(a.z), acc[5]);
                acc[6]  = fmaf(w, bf_lo(a.w), acc[6]);
                acc[7]  = fmaf(w, bf_hi(a.w), acc[7]);
                acc[8]  = fmaf(w, bf_lo(c.x), acc[8]);
                acc[9]  = fmaf(w, bf_hi(c.x), acc[9]);
                acc[10] = fmaf(w, bf_lo(c.y), acc[10]);
                acc[11] = fmaf(w, bf_hi(c.y), acc[11]);
                acc[12] = fmaf(w, bf_lo(c.z), acc[12]);
                acc[13] = fmaf(w, bf_hi(c.z), acc[13]);
                acc[14] = fmaf(w, bf_lo(c.w), acc[14]);
                acc[15] = fmaf(w, bf_hi(c.w), acc[15]);
            }
        }

        // 4-lane pre-reduce, then 128 writers store to red
        #pragma unroll
        for (int o = 0; o < 16; ++o) {
            acc[o] += __shfl_xor(acc[o], 1, 64);
            acc[o] += __shfl_xor(acc[o], 2, 64);
        }
        if ((t & 3) == 0) {
            const int w = t >> 2;                  // 0..127
            float* dst = red + w * 20;
            *(float4*)(dst + 0)  = make_float4(acc[0],  acc[1],  acc[2],  acc[3]);
            *(float4*)(dst + 4)  = make_float4(acc[4],  acc[5],  acc[6],  acc[7]);
            *(float4*)(dst + 8)  = make_float4(acc[8],  acc[9],  acc[10], acc[11]);
            *(float4*)(dst + 12) = make_float4(acc[12], acc[13], acc[14], acc[15]);
        }
        __syncthreads();                           // bar1

        // stage 2: 256 threads, (o = t&15, g = t>>4 in 0..15) sum 8 writers each
        if (t < 256) {
            const int o = t & 15, g = t >> 4;
            float s = 0.f;
            #pragma unroll
            for (int j = 0; j < 8; ++j)
                s += red[(g * 8 + j) * 20 + o];
            part[(g << 4) + o] = s;
        }
        __syncthreads();                           // bar2

        // stage 3: 16 threads finish s_o
        if (t < 16) {
            float s = 0.f;
            #pragma unroll
            for (int g = 0; g < 16; ++g) s += part[(g << 4) + t];
            float Z;
            if (round == 0) {
                Z = (float)R_ROUTES;
            } else {
                Z = sred[0] + sred[1] + sred[2] + sred[3]
                  + sred[4] + sred[5] + sred[6] + sred[7];
            }
            sv[t] = s / Z;
        }
        __syncthreads();                           // bar3

        // squash factor from LDS broadcasts (same-address reads: free)
        float svr[16];
        float sn = 0.f;
        #pragma unroll
        for (int o = 0; o < 16; ++o) { svr[o] = sv[o]; sn = fmaf(svr[o], svr[o], sn); }
        const float factor = sn / ((1.0f + sn) * sqrtf(sn));

        if (round == NUM_ROUNDS - 1) {
            if (t < 16) out[(size_t)blk * COUT + t] = factor * svr[t];
        } else {
            // logit update: re-read owned rows (cheap b128), dot with v
            #pragma unroll
            for (int k = 0; k < 3; ++k) {
                if (k < nr) {
                    const int r = t + (k << 9);
                    const uint4 a = *(const uint4*)(pbuf + r * 8);
                    const uint4 c = *(const uint4*)(pbuf + r * 8 + 4);
                    float d;
                    d = svr[0] * bf_lo(a.x);
                    d = fmaf(svr[1],  bf_hi(a.x), d);
                    d = fmaf(svr[2],  bf_lo(a.y), d);
                    d = fmaf(svr[3],  bf_hi(a.y), d);
                    d = fmaf(svr[4],  bf_lo(a.z), d);
                    d = fmaf(svr[5],  bf_hi(a.z), d);
                    d = fmaf(svr[6],  bf_lo(a.w), d);
                    d = fmaf(svr[7],  bf_hi(a.w), d);
                    d = fmaf(svr[8],  bf_lo(c.x), d);
                    d = fmaf(svr[9],  bf_hi(c.x), d);
                    d = fmaf(svr[10], bf_lo(c.y), d);
                    d = fmaf(svr[11], bf_hi(c.y), d);
                    d = fmaf(svr[12], bf_lo(c.z), d);
                    d = fmaf(svr[13], bf_hi(c.z), d);
                    d = fmaf(svr[14], bf_lo(c.w), d);
                    d = fmaf(svr[15], bf_hi(c.w), d);
                    if (k == 0)      bl0 = fmaf(factor, d, bl0);
                    else if (k == 1) bl1 = fmaf(factor, d, bl1);
                    else             bl2 = fmaf(factor, d, bl2);
                }
            }
            // no barrier: next round's cross-thread LDS writes are separated
            // from this round's reads by bar1/bar3 ordering.
        }
    }
}

extern "C" void kernel_launch(void* const* d_in, const int* in_sizes, int n_in,
                              void* d_out, int out_size, void* d_ws, size_t ws_size,
                              hipStream_t stream) {
    const float* x = (const float*)d_in[0];   // [512, 1152, 8] fp32
    const float* W = (const float*)d_in[1];   // [10, 1152, 8, 16] fp32
    float* out = (float*)d_out;               // [10, 512, 1, 1, 16] fp32

    dim3 grid(NCAPS * BATCH);                 // 5120 blocks, n-major
    dim3 block(512);
    capsule_routing_bf<<<grid, block, 0, stream>>>(x, W, out);
}

// Round 5
// 193.544 us; speedup vs baseline: 9.9325x; 2.8787x over previous
//
#include <hip/hip_runtime.h>
#include <math.h>

#define R_ROUTES 1152
#define CIN 8
#define COUT 16
#define BATCH 512
#define NCAPS 10
#define NUM_ROUNDS 3

// f32 -> bf16 round-to-nearest-even
__device__ __forceinline__ unsigned int bf16_rne(float f) {
    unsigned int u = __float_as_uint(f);
    u += 0x7fffu + ((u >> 16) & 1u);
    return u >> 16;
}
__device__ __forceinline__ unsigned int pack2(float lo, float hi) {
    return bf16_rne(lo) | (bf16_rne(hi) << 16);
}
__device__ __forceinline__ float bf_lo(unsigned int u) { return __uint_as_float(u << 16); }
__device__ __forceinline__ float bf_hi(unsigned int u) { return __uint_as_float(u & 0xffff0000u); }

// Swizzled 16-B-unit index for (row r, half h). XOR with (r>>2)&7 is a
// bijection within each aligned 128-B (8-unit / 4-row) group and spreads
// 64 consecutive-r lanes uniformly over all 8 bank groups -> ds_read_b128
// at 32-B row stride becomes conflict-free.
__device__ __forceinline__ int sunit(int r, int h) {
    return (2 * r + h) ^ ((r >> 2) & 7);
}

// 256 threads per (n,b). Phase A: quad-cooperative (4 lanes/row, coalesced
// 64-B quads), 2 rows in flight -> 20 outstanding dwordx4/thread.
// Phase B: thread t owns rows r = t + 256k (5 if t<128 else 4), priors
// bf16-packed + swizzled in LDS. LDS ~42 KB -> 3 blocks/CU = 12 waves.
extern "C" __global__ void __launch_bounds__(256, 3)
capsule_routing_v5(const float* __restrict__ x,
                   const float* __restrict__ W,
                   float* __restrict__ out)
{
    __shared__ unsigned int pbuf[R_ROUTES * 8];   // 36864 B bf16 priors (swizzled)
    __shared__ float red[64 * 20];                // 5120 B writer scratch (16B-aligned rows)
    __shared__ float part[256];                   // 1024 B
    __shared__ float sred[4];                     // per-wave exp sums
    __shared__ float sv[16];                      // s vector

    const int blk = blockIdx.x;                   // n-major: W[n] stays L2-resident
    const int n = blk >> 9;
    const int b = blk & 511;
    const int t = threadIdx.x;

    const float* __restrict__ xrow = x + (size_t)b * (R_ROUTES * CIN);
    const float* __restrict__ Wn = W + (size_t)n * (R_ROUTES * CIN * COUT);

    // ---------------- Phase A: quad-cooperative priors -> swizzled bf16 LDS
    {
        const int oq = t & 3;                     // column quad: o in [4*oq, 4*oq+4)
        const int rsub = t >> 2;                  // 0..63
        const int subw = (oq & 1) * 2;            // u32 sub-offset within 16-B unit
        const int hq = oq >> 1;                   // which 16-B half this quad fills

        for (int itp = 0; itp < 18; itp += 2) {   // two rows in flight
            const int ra = itp * 64 + rsub;
            const int rb = ra + 64;
            const float4* __restrict__ wpa = (const float4*)(Wn + (size_t)ra * 128) + oq;
            const float4* __restrict__ wpb = (const float4*)(Wn + (size_t)rb * 128) + oq;
            float4 wA[8], wB[8];
            #pragma unroll
            for (int i = 0; i < 8; ++i) wA[i] = wpa[i * 4];
            #pragma unroll
            for (int i = 0; i < 8; ++i) wB[i] = wpb[i * 4];
            const float4 xa0 = *(const float4*)(xrow + ra * 8);
            const float4 xa1 = *(const float4*)(xrow + ra * 8 + 4);
            const float4 xb0 = *(const float4*)(xrow + rb * 8);
            const float4 xb1 = *(const float4*)(xrow + rb * 8 + 4);

            {   // row ra
                const float xs[8] = {xa0.x, xa0.y, xa0.z, xa0.w,
                                     xa1.x, xa1.y, xa1.z, xa1.w};
                float a0 = 0.f, a1 = 0.f, a2 = 0.f, a3 = 0.f;
                #pragma unroll
                for (int i = 0; i < 8; ++i) {
                    a0 = fmaf(xs[i], wA[i].x, a0);
                    a1 = fmaf(xs[i], wA[i].y, a1);
                    a2 = fmaf(xs[i], wA[i].z, a2);
                    a3 = fmaf(xs[i], wA[i].w, a3);
                }
                uint2 u; u.x = pack2(a0, a1); u.y = pack2(a2, a3);
                *(uint2*)(pbuf + sunit(ra, hq) * 4 + subw) = u;
            }
            {   // row rb
                const float xs[8] = {xb0.x, xb0.y, xb0.z, xb0.w,
                                     xb1.x, xb1.y, xb1.z, xb1.w};
                float a0 = 0.f, a1 = 0.f, a2 = 0.f, a3 = 0.f;
                #pragma unroll
                for (int i = 0; i < 8; ++i) {
                    a0 = fmaf(xs[i], wB[i].x, a0);
                    a1 = fmaf(xs[i], wB[i].y, a1);
                    a2 = fmaf(xs[i], wB[i].z, a2);
                    a3 = fmaf(xs[i], wB[i].w, a3);
                }
                uint2 u; u.x = pack2(a0, a1); u.y = pack2(a2, a3);
                *(uint2*)(pbuf + sunit(rb, hq) * 4 + subw) = u;
            }
        }
    }
    __syncthreads();   // quad writers -> owner readers

    // ---------------- Phase B: 3 routing rounds (owner rows r = t + 256k)
    const int nr = (t < 128) ? 5 : 4;             // wave-uniform
    float bl[5] = {0.f, 0.f, 0.f, 0.f, 0.f};

    for (int round = 0; round < NUM_ROUNDS; ++round) {
        float e[5];
        if (round == 0) {
            #pragma unroll
            for (int k = 0; k < 5; ++k) e[k] = 1.f;
        } else {
            float es = 0.f;
            #pragma unroll
            for (int k = 0; k < 5; ++k) {
                e[k] = (k < nr) ? __expf(bl[k]) : 0.f;
                es += e[k];
            }
            #pragma unroll
            for (int off = 32; off > 0; off >>= 1) es += __shfl_xor(es, off, 64);
            if ((t & 63) == 0) sred[t >> 6] = es;  // consumed after bar2
        }

        // owner-local weighted sum
        float acc[16];
        #pragma unroll
        for (int o = 0; o < 16; ++o) acc[o] = 0.f;
        #pragma unroll
        for (int k = 0; k < 5; ++k) {
            if (k < nr) {
                const int r = t + (k << 8);
                const uint4 a = *(const uint4*)(pbuf + sunit(r, 0) * 4);
                const uint4 c = *(const uint4*)(pbuf + sunit(r, 1) * 4);
                const float w = e[k];
                acc[0]  = fmaf(w, bf_lo(a.x), acc[0]);
                acc[1]  = fmaf(w, bf_hi(a.x), acc[1]);
                acc[2]  = fmaf(w, bf_lo(a.y), acc[2]);
                acc[3]  = fmaf(w, bf_hi(a.y), acc[3]);
                acc[4]  = fmaf(w, bf_lo(a.z), acc[4]);
                acc[5]  = fmaf(w, bf_hi(a.z), acc[5]);
                acc[6]  = fmaf(w, bf_lo(a.w), acc[6]);
                acc[7]  = fmaf(w, bf_hi(a.w), acc[7]);
                acc[8]  = fmaf(w, bf_lo(c.x), acc[8]);
                acc[9]  = fmaf(w, bf_hi(c.x), acc[9]);
                acc[10] = fmaf(w, bf_lo(c.y), acc[10]);
                acc[11] = fmaf(w, bf_hi(c.y), acc[11]);
                acc[12] = fmaf(w, bf_lo(c.z), acc[12]);
                acc[13] = fmaf(w, bf_hi(c.z), acc[13]);
                acc[14] = fmaf(w, bf_lo(c.w), acc[14]);
                acc[15] = fmaf(w, bf_hi(c.w), acc[15]);
            }
        }

        // 4-lane shuffle pre-reduce -> 64 LDS writers
        #pragma unroll
        for (int o = 0; o < 16; ++o) {
            acc[o] += __shfl_xor(acc[o], 1, 64);
            acc[o] += __shfl_xor(acc[o], 2, 64);
        }
        if ((t & 3) == 0) {
            float* dst = red + (t >> 2) * 20;     // 80-B stride: aligned, banks spread
            *(float4*)(dst + 0)  = make_float4(acc[0],  acc[1],  acc[2],  acc[3]);
            *(float4*)(dst + 4)  = make_float4(acc[4],  acc[5],  acc[6],  acc[7]);
            *(float4*)(dst + 8)  = make_float4(acc[8],  acc[9],  acc[10], acc[11]);
            *(float4*)(dst + 12) = make_float4(acc[12], acc[13], acc[14], acc[15]);
        }
        __syncthreads();                          // bar1

        // stage 2: (o = t&15, g = t>>4) sums 4 writers each
        {
            const int o = t & 15, g = t >> 4;
            float s = 0.f;
            #pragma unroll
            for (int j = 0; j < 4; ++j)
                s += red[((g << 2) + j) * 20 + o];
            part[(g << 4) + o] = s;
        }
        __syncthreads();                          // bar2

        // stage 3: 16 threads finish s_o
        if (t < 16) {
            float s = 0.f;
            #pragma unroll
            for (int g = 0; g < 16; ++g) s += part[(g << 4) + t];
            const float Z = (round == 0)
                ? (float)R_ROUTES
                : (sred[0] + sred[1] + sred[2] + sred[3]);
            sv[t] = s / Z;
        }
        __syncthreads();                          // bar3

        // squash factor (same-address LDS reads broadcast: free)
        float svr[16];
        float sn = 0.f;
        #pragma unroll
        for (int o = 0; o < 16; ++o) { svr[o] = sv[o]; sn = fmaf(svr[o], svr[o], sn); }
        const float factor = sn / ((1.0f + sn) * sqrtf(sn));

        if (round == NUM_ROUNDS - 1) {
            if (t < 16) out[(size_t)blk * COUT + t] = factor * svr[t];
        } else {
            // logit update: re-read owned rows (conflict-free b128)
            #pragma unroll
            for (int k = 0; k < 5; ++k) {
                if (k < nr) {
                    const int r = t + (k << 8);
                    const uint4 a = *(const uint4*)(pbuf + sunit(r, 0) * 4);
                    const uint4 c = *(const uint4*)(pbuf + sunit(r, 1) * 4);
                    float d;
                    d = svr[0] * bf_lo(a.x);
                    d = fmaf(svr[1],  bf_hi(a.x), d);
                    d = fmaf(svr[2],  bf_lo(a.y), d);
                    d = fmaf(svr[3],  bf_hi(a.y), d);
                    d = fmaf(svr[4],  bf_lo(a.z), d);
                    d = fmaf(svr[5],  bf_hi(a.z), d);
                    d = fmaf(svr[6],  bf_lo(a.w), d);
                    d = fmaf(svr[7],  bf_hi(a.w), d);
                    d = fmaf(svr[8],  bf_lo(c.x), d);
                    d = fmaf(svr[9],  bf_hi(c.x), d);
                    d = fmaf(svr[10], bf_lo(c.y), d);
                    d = fmaf(svr[11], bf_hi(c.y), d);
                    d = fmaf(svr[12], bf_lo(c.z), d);
                    d = fmaf(svr[13], bf_hi(c.z), d);
                    d = fmaf(svr[14], bf_lo(c.w), d);
                    d = fmaf(svr[15], bf_hi(c.w), d);
                    bl[k] = fmaf(factor, d, bl[k]);
                }
            }
            // no barrier: next round's cross-thread LDS writes are ordered
            // by bar1..bar3 against this round's reads.
        }
    }
}

extern "C" void kernel_launch(void* const* d_in, const int* in_sizes, int n_in,
                              void* d_out, int out_size, void* d_ws, size_t ws_size,
                              hipStream_t stream) {
    const float* x = (const float*)d_in[0];   // [512, 1152, 8] fp32
    const float* W = (const float*)d_in[1];   // [10, 1152, 8, 16] fp32
    float* out = (float*)d_out;               // [10, 512, 1, 1, 16] fp32

    dim3 grid(NCAPS * BATCH);                 // 5120 blocks, n-major
    dim3 block(256);
    capsule_routing_v5<<<grid, block, 0, stream>>>(x, W, out);
}

// Round 6
// 182.020 us; speedup vs baseline: 10.5613x; 1.0633x over previous
//
#include <hip/hip_runtime.h>
#include <math.h>

#define R_ROUTES 1152
#define CIN 8
#define COUT 16
#define BATCH 512
#define NCAPS 10
#define NUM_ROUNDS 3

// f32 -> bf16 round-to-nearest-even
__device__ __forceinline__ unsigned int bf16_rne(float f) {
    unsigned int u = __float_as_uint(f);
    u += 0x7fffu + ((u >> 16) & 1u);
    return u >> 16;
}
__device__ __forceinline__ unsigned int pack2(float lo, float hi) {
    return bf16_rne(lo) | (bf16_rne(hi) << 16);
}
__device__ __forceinline__ float bf_lo(unsigned int u) { return __uint_as_float(u << 16); }
__device__ __forceinline__ float bf_hi(unsigned int u) { return __uint_as_float(u & 0xffff0000u); }

// Swizzled 16-B-unit index for (row r, half h): bijection within each 128-B
// group, spreads consecutive-r b128 reads over all 8 bank groups (R5-verified).
__device__ __forceinline__ int sunit(int r, int h) {
    return (2 * r + h) ^ ((r >> 2) & 7);
}

// 512 threads per (n, b-pair): W[n] row loaded ONCE serves both batches
// (halves W L2 traffic). Phase A: 128 quads x 9 rows, coalesced 64-B W quads.
// Phase B: two 256-thread halves, each runs routing on its own batch.
// LDS 81,056 B -> 2 blocks/CU = 16 waves/CU.
extern "C" __global__ void __launch_bounds__(512, 4)
capsule_routing_v6(const float* __restrict__ x,
                   const float* __restrict__ W,
                   float* __restrict__ out)
{
    __shared__ unsigned int pbuf[2 * R_ROUTES * 8];  // 73728 B bf16 priors (swizzled)
    __shared__ float red[2 * 32 * 20];               // 5120 B writer scratch
    __shared__ float part[2 * 256];                  // 2048 B
    __shared__ float sred[2 * 4];                    // per-wave exp sums
    __shared__ float sv[2 * 16];                     // s vectors

    const int blk = blockIdx.x;                      // n-major: W[n] L2-resident
    const int n = blk >> 8;
    const int bp = blk & 255;
    const int t = threadIdx.x;

    const float* __restrict__ x0 = x + (size_t)(2 * bp) * (R_ROUTES * CIN);
    const float* __restrict__ x1 = x0 + R_ROUTES * CIN;
    const float* __restrict__ Wn = W + (size_t)n * (R_ROUTES * CIN * COUT);

    // ---------------- Phase A: one W row -> priors for BOTH batches
    {
        const int q = t >> 2;                        // 0..127
        const int oq = t & 3;                        // column quad
        const int subw = (oq & 1) * 2;               // u32 sub-offset in 16-B unit
        const int hq = oq >> 1;                      // which 16-B half

        #pragma unroll 3
        for (int it = 0; it < 9; ++it) {
            const int r = it * 128 + q;
            const float4* __restrict__ wp = (const float4*)(Wn + (size_t)r * 128) + oq;
            float4 wv[8];
            #pragma unroll
            for (int i = 0; i < 8; ++i) wv[i] = wp[i * 4];
            const float4 xa0 = *(const float4*)(x0 + r * 8);
            const float4 xa1 = *(const float4*)(x0 + r * 8 + 4);
            const float4 xb0 = *(const float4*)(x1 + r * 8);
            const float4 xb1 = *(const float4*)(x1 + r * 8 + 4);

            {   // batch 0
                const float xs[8] = {xa0.x, xa0.y, xa0.z, xa0.w,
                                     xa1.x, xa1.y, xa1.z, xa1.w};
                float a0 = 0.f, a1 = 0.f, a2 = 0.f, a3 = 0.f;
                #pragma unroll
                for (int i = 0; i < 8; ++i) {
                    a0 = fmaf(xs[i], wv[i].x, a0);
                    a1 = fmaf(xs[i], wv[i].y, a1);
                    a2 = fmaf(xs[i], wv[i].z, a2);
                    a3 = fmaf(xs[i], wv[i].w, a3);
                }
                uint2 u; u.x = pack2(a0, a1); u.y = pack2(a2, a3);
                *(uint2*)(pbuf + sunit(r, hq) * 4 + subw) = u;
            }
            {   // batch 1
                const float xs[8] = {xb0.x, xb0.y, xb0.z, xb0.w,
                                     xb1.x, xb1.y, xb1.z, xb1.w};
                float a0 = 0.f, a1 = 0.f, a2 = 0.f, a3 = 0.f;
                #pragma unroll
                for (int i = 0; i < 8; ++i) {
                    a0 = fmaf(xs[i], wv[i].x, a0);
                    a1 = fmaf(xs[i], wv[i].y, a1);
                    a2 = fmaf(xs[i], wv[i].z, a2);
                    a3 = fmaf(xs[i], wv[i].w, a3);
                }
                uint2 u; u.x = pack2(a0, a1); u.y = pack2(a2, a3);
                *(uint2*)(pbuf + R_ROUTES * 8 + sunit(r, hq) * 4 + subw) = u;
            }
        }
    }
    __syncthreads();   // Phase A writers -> Phase B owners

    // ---------------- Phase B: two 256-thread halves, one batch each
    const int half = t >> 8;                         // 0 or 1 (wave-aligned)
    const int tt = t & 255;
    unsigned int* __restrict__ pb = pbuf + half * (R_ROUTES * 8);
    float* __restrict__ redh = red + half * (32 * 20);
    float* __restrict__ parth = part + half * 256;
    float* __restrict__ sredh = sred + half * 4;
    float* __restrict__ svh = sv + half * 16;

    const int nr = (tt < 128) ? 5 : 4;               // wave-uniform
    float bl[5] = {0.f, 0.f, 0.f, 0.f, 0.f};

    for (int round = 0; round < NUM_ROUNDS; ++round) {
        float e[5];
        if (round == 0) {
            #pragma unroll
            for (int k = 0; k < 5; ++k) e[k] = 1.f;
        } else {
            float es = 0.f;
            #pragma unroll
            for (int k = 0; k < 5; ++k) {
                e[k] = (k < nr) ? __expf(bl[k]) : 0.f;
                es += e[k];
            }
            #pragma unroll
            for (int off = 32; off > 0; off >>= 1) es += __shfl_xor(es, off, 64);
            if ((t & 63) == 0) sredh[tt >> 6] = es;  // consumed after bar2
        }

        // owner-local weighted sum over rows r = tt + 256k
        float acc[16];
        #pragma unroll
        for (int o = 0; o < 16; ++o) acc[o] = 0.f;
        #pragma unroll
        for (int k = 0; k < 5; ++k) {
            if (k < nr) {
                const int r = tt + (k << 8);
                const uint4 a = *(const uint4*)(pb + sunit(r, 0) * 4);
                const uint4 c = *(const uint4*)(pb + sunit(r, 1) * 4);
                const float w = e[k];
                acc[0]  = fmaf(w, bf_lo(a.x), acc[0]);
                acc[1]  = fmaf(w, bf_hi(a.x), acc[1]);
                acc[2]  = fmaf(w, bf_lo(a.y), acc[2]);
                acc[3]  = fmaf(w, bf_hi(a.y), acc[3]);
                acc[4]  = fmaf(w, bf_lo(a.z), acc[4]);
                acc[5]  = fmaf(w, bf_hi(a.z), acc[5]);
                acc[6]  = fmaf(w, bf_lo(a.w), acc[6]);
                acc[7]  = fmaf(w, bf_hi(a.w), acc[7]);
                acc[8]  = fmaf(w, bf_lo(c.x), acc[8]);
                acc[9]  = fmaf(w, bf_hi(c.x), acc[9]);
                acc[10] = fmaf(w, bf_lo(c.y), acc[10]);
                acc[11] = fmaf(w, bf_hi(c.y), acc[11]);
                acc[12] = fmaf(w, bf_lo(c.z), acc[12]);
                acc[13] = fmaf(w, bf_hi(c.z), acc[13]);
                acc[14] = fmaf(w, bf_lo(c.w), acc[14]);
                acc[15] = fmaf(w, bf_hi(c.w), acc[15]);
            }
        }

        // 8-lane shuffle pre-reduce -> 32 LDS writers per half
        #pragma unroll
        for (int o = 0; o < 16; ++o) {
            acc[o] += __shfl_xor(acc[o], 1, 64);
            acc[o] += __shfl_xor(acc[o], 2, 64);
            acc[o] += __shfl_xor(acc[o], 4, 64);
        }
        if ((tt & 7) == 0) {
            float* dst = redh + (tt >> 3) * 20;      // 80-B stride: conflict-free b128
            *(float4*)(dst + 0)  = make_float4(acc[0],  acc[1],  acc[2],  acc[3]);
            *(float4*)(dst + 4)  = make_float4(acc[4],  acc[5],  acc[6],  acc[7]);
            *(float4*)(dst + 8)  = make_float4(acc[8],  acc[9],  acc[10], acc[11]);
            *(float4*)(dst + 12) = make_float4(acc[12], acc[13], acc[14], acc[15]);
        }
        __syncthreads();                             // bar1

        // stage 2: (o = tt&15, g = tt>>4) sums 2 writers each
        {
            const int o = tt & 15, g = tt >> 4;
            parth[(g << 4) + o] =
                redh[((g << 1) + 0) * 20 + o] + redh[((g << 1) + 1) * 20 + o];
        }
        __syncthreads();                             // bar2

        // stage 3: 16 threads per half finish s_o
        if (tt < 16) {
            float s = 0.f;
            #pragma unroll
            for (int g = 0; g < 16; ++g) s += parth[(g << 4) + tt];
            const float Z = (round == 0)
                ? (float)R_ROUTES
                : (sredh[0] + sredh[1] + sredh[2] + sredh[3]);
            svh[tt] = s / Z;
        }
        __syncthreads();                             // bar3

        // squash factor (same-address LDS reads broadcast: free)
        float svr[16];
        float sn = 0.f;
        #pragma unroll
        for (int o = 0; o < 16; ++o) { svr[o] = svh[o]; sn = fmaf(svr[o], svr[o], sn); }
        const float factor = sn / ((1.0f + sn) * sqrtf(sn));

        if (round == NUM_ROUNDS - 1) {
            if (tt < 16)
                out[((size_t)n * BATCH + 2 * bp + half) * COUT + tt] = factor * svr[tt];
        } else {
            // logit update: re-read owned rows (conflict-free b128)
            #pragma unroll
            for (int k = 0; k < 5; ++k) {
                if (k < nr) {
                    const int r = tt + (k << 8);
                    const uint4 a = *(const uint4*)(pb + sunit(r, 0) * 4);
                    const uint4 c = *(const uint4*)(pb + sunit(r, 1) * 4);
                    float d;
                    d = svr[0] * bf_lo(a.x);
                    d = fmaf(svr[1],  bf_hi(a.x), d);
                    d = fmaf(svr[2],  bf_lo(a.y), d);
                    d = fmaf(svr[3],  bf_hi(a.y), d);
                    d = fmaf(svr[4],  bf_lo(a.z), d);
                    d = fmaf(svr[5],  bf_hi(a.z), d);
                    d = fmaf(svr[6],  bf_lo(a.w), d);
                    d = fmaf(svr[7],  bf_hi(a.w), d);
                    d = fmaf(svr[8],  bf_lo(c.x), d);
                    d = fmaf(svr[9],  bf_hi(c.x), d);
                    d = fmaf(svr[10], bf_lo(c.y), d);
                    d = fmaf(svr[11], bf_hi(c.y), d);
                    d = fmaf(svr[12], bf_lo(c.z), d);
                    d = fmaf(svr[13], bf_hi(c.z), d);
                    d = fmaf(svr[14], bf_lo(c.w), d);
                    d = fmaf(svr[15], bf_hi(c.w), d);
                    bl[k] = fmaf(factor, d, bl[k]);
                }
            }
            // no barrier: next round's cross-thread LDS writes are ordered
            // by bar1..bar3 against this round's reads.
        }
    }
}

extern "C" void kernel_launch(void* const* d_in, const int* in_sizes, int n_in,
                              void* d_out, int out_size, void* d_ws, size_t ws_size,
                              hipStream_t stream) {
    const float* x = (const float*)d_in[0];   // [512, 1152, 8] fp32
    const float* W = (const float*)d_in[1];   // [10, 1152, 8, 16] fp32
    float* out = (float*)d_out;               // [10, 512, 1, 1, 16] fp32

    dim3 grid(NCAPS * (BATCH / 2));           // 2560 blocks, n-major
    dim3 block(512);
    capsule_routing_v6<<<grid, block, 0, stream>>>(x, W, out);
}

// Round 7
// 161.741 us; speedup vs baseline: 11.8855x; 1.1254x over previous
//
#include <hip/hip_runtime.h>
#include <math.h>

#define R_ROUTES 1152
#define CIN 8
#define COUT 16
#define BATCH 512
#define NCAPS 10
#define NUM_ROUNDS 3

// f32 -> bf16 round-to-nearest-even
__device__ __forceinline__ unsigned int bf16_rne(float f) {
    unsigned int u = __float_as_uint(f);
    u += 0x7fffu + ((u >> 16) & 1u);
    return u >> 16;
}
__device__ __forceinline__ unsigned int pack2(float lo, float hi) {
    return bf16_rne(lo) | (bf16_rne(hi) << 16);
}
__device__ __forceinline__ float bf_lo(unsigned int u) { return __uint_as_float(u << 16); }
__device__ __forceinline__ float bf_hi(unsigned int u) { return __uint_as_float(u & 0xffff0000u); }

// Swizzled 16-B-unit index for (row r, half h): bijection within each 128-B
// group, spreads consecutive-r b128 reads over all 8 bank groups (R5-verified).
__device__ __forceinline__ int sunit(int r, int h) {
    return (2 * r + h) ^ ((r >> 2) & 7);
}

// 512 threads per (n, b-pair): W[n] row loaded ONCE serves both batches.
// Phase A: 128 quads x 9 rows, coalesced 64-B W quads. NO unroll: one
// iteration = 12 dwordx4 in flight, live set ~56 regs (R6's unroll-3
// spilled at the 128-reg cap -> 87 MB scratch writes; this is the fix).
// Phase B: two 256-thread halves, each routes its own batch.
// LDS 81,408 B -> 2 blocks/CU = 16 waves/CU.
extern "C" __global__ void __launch_bounds__(512, 4)
capsule_routing_v7(const float* __restrict__ x,
                   const float* __restrict__ W,
                   float* __restrict__ out)
{
    __shared__ unsigned int pbuf[2 * R_ROUTES * 8];  // 73728 B bf16 priors (swizzled)
    __shared__ float red[2 * 32 * 20];               // 5120 B writer scratch
    __shared__ float part[2 * 256];                  // 2048 B
    __shared__ float sred[2 * 4];                    // per-wave exp sums
    __shared__ float sv[2 * 16];                     // s vectors

    const int blk = blockIdx.x;                      // n-major: W[n] L2-resident
    const int n = blk >> 8;
    const int bp = blk & 255;
    const int t = threadIdx.x;

    const float* __restrict__ x0 = x + (size_t)(2 * bp) * (R_ROUTES * CIN);
    const float* __restrict__ x1 = x0 + R_ROUTES * CIN;
    const float* __restrict__ Wn = W + (size_t)n * (R_ROUTES * CIN * COUT);

    // ---------------- Phase A: one W row -> priors for BOTH batches
    {
        const int q = t >> 2;                        // 0..127
        const int oq = t & 3;                        // column quad
        const int subw = (oq & 1) * 2;               // u32 sub-offset in 16-B unit
        const int hq = oq >> 1;                      // which 16-B half

        #pragma unroll 1
        for (int it = 0; it < 9; ++it) {
            const int r = it * 128 + q;
            const float4* __restrict__ wp = (const float4*)(Wn + (size_t)r * 128) + oq;
            float4 wv[8];
            #pragma unroll
            for (int i = 0; i < 8; ++i) wv[i] = wp[i * 4];
            const float4 xa0 = *(const float4*)(x0 + r * 8);
            const float4 xa1 = *(const float4*)(x0 + r * 8 + 4);
            const float4 xb0 = *(const float4*)(x1 + r * 8);
            const float4 xb1 = *(const float4*)(x1 + r * 8 + 4);

            {   // batch 0
                const float xs[8] = {xa0.x, xa0.y, xa0.z, xa0.w,
                                     xa1.x, xa1.y, xa1.z, xa1.w};
                float a0 = 0.f, a1 = 0.f, a2 = 0.f, a3 = 0.f;
                #pragma unroll
                for (int i = 0; i < 8; ++i) {
                    a0 = fmaf(xs[i], wv[i].x, a0);
                    a1 = fmaf(xs[i], wv[i].y, a1);
                    a2 = fmaf(xs[i], wv[i].z, a2);
                    a3 = fmaf(xs[i], wv[i].w, a3);
                }
                uint2 u; u.x = pack2(a0, a1); u.y = pack2(a2, a3);
                *(uint2*)(pbuf + sunit(r, hq) * 4 + subw) = u;
            }
            {   // batch 1
                const float xs[8] = {xb0.x, xb0.y, xb0.z, xb0.w,
                                     xb1.x, xb1.y, xb1.z, xb1.w};
                float a0 = 0.f, a1 = 0.f, a2 = 0.f, a3 = 0.f;
                #pragma unroll
                for (int i = 0; i < 8; ++i) {
                    a0 = fmaf(xs[i], wv[i].x, a0);
                    a1 = fmaf(xs[i], wv[i].y, a1);
                    a2 = fmaf(xs[i], wv[i].z, a2);
                    a3 = fmaf(xs[i], wv[i].w, a3);
                }
                uint2 u; u.x = pack2(a0, a1); u.y = pack2(a2, a3);
                *(uint2*)(pbuf + R_ROUTES * 8 + sunit(r, hq) * 4 + subw) = u;
            }
        }
    }
    __syncthreads();   // Phase A writers -> Phase B owners

    // ---------------- Phase B: two 256-thread halves, one batch each
    const int half = t >> 8;                         // 0 or 1 (wave-aligned)
    const int tt = t & 255;
    unsigned int* __restrict__ pb = pbuf + half * (R_ROUTES * 8);
    float* __restrict__ redh = red + half * (32 * 20);
    float* __restrict__ parth = part + half * 256;
    float* __restrict__ sredh = sred + half * 4;
    float* __restrict__ svh = sv + half * 16;

    const int nr = (tt < 128) ? 5 : 4;               // wave-uniform
    float bl[5] = {0.f, 0.f, 0.f, 0.f, 0.f};

    for (int round = 0; round < NUM_ROUNDS; ++round) {
        float e[5];
        if (round == 0) {
            #pragma unroll
            for (int k = 0; k < 5; ++k) e[k] = 1.f;
        } else {
            float es = 0.f;
            #pragma unroll
            for (int k = 0; k < 5; ++k) {
                e[k] = (k < nr) ? __expf(bl[k]) : 0.f;
                es += e[k];
            }
            #pragma unroll
            for (int off = 32; off > 0; off >>= 1) es += __shfl_xor(es, off, 64);
            if ((t & 63) == 0) sredh[tt >> 6] = es;  // consumed after bar2
        }

        // owner-local weighted sum over rows r = tt + 256k
        float acc[16];
        #pragma unroll
        for (int o = 0; o < 16; ++o) acc[o] = 0.f;
        #pragma unroll
        for (int k = 0; k < 5; ++k) {
            if (k < nr) {
                const int r = tt + (k << 8);
                const uint4 a = *(const uint4*)(pb + sunit(r, 0) * 4);
                const uint4 c = *(const uint4*)(pb + sunit(r, 1) * 4);
                const float w = e[k];
                acc[0]  = fmaf(w, bf_lo(a.x), acc[0]);
                acc[1]  = fmaf(w, bf_hi(a.x), acc[1]);
                acc[2]  = fmaf(w, bf_lo(a.y), acc[2]);
                acc[3]  = fmaf(w, bf_hi(a.y), acc[3]);
                acc[4]  = fmaf(w, bf_lo(a.z), acc[4]);
                acc[5]  = fmaf(w, bf_hi(a.z), acc[5]);
                acc[6]  = fmaf(w, bf_lo(a.w), acc[6]);
                acc[7]  = fmaf(w, bf_hi(a.w), acc[7]);
                acc[8]  = fmaf(w, bf_lo(c.x), acc[8]);
                acc[9]  = fmaf(w, bf_hi(c.x), acc[9]);
                acc[10] = fmaf(w, bf_lo(c.y), acc[10]);
                acc[11] = fmaf(w, bf_hi(c.y), acc[11]);
                acc[12] = fmaf(w, bf_lo(c.z), acc[12]);
                acc[13] = fmaf(w, bf_hi(c.z), acc[13]);
                acc[14] = fmaf(w, bf_lo(c.w), acc[14]);
                acc[15] = fmaf(w, bf_hi(c.w), acc[15]);
            }
        }

        // 8-lane shuffle pre-reduce -> 32 LDS writers per half
        #pragma unroll
        for (int o = 0; o < 16; ++o) {
            acc[o] += __shfl_xor(acc[o], 1, 64);
            acc[o] += __shfl_xor(acc[o], 2, 64);
            acc[o] += __shfl_xor(acc[o], 4, 64);
        }
        if ((tt & 7) == 0) {
            float* dst = redh + (tt >> 3) * 20;      // 80-B stride: conflict-free b128
            *(float4*)(dst + 0)  = make_float4(acc[0],  acc[1],  acc[2],  acc[3]);
            *(float4*)(dst + 4)  = make_float4(acc[4],  acc[5],  acc[6],  acc[7]);
            *(float4*)(dst + 8)  = make_float4(acc[8],  acc[9],  acc[10], acc[11]);
            *(float4*)(dst + 12) = make_float4(acc[12], acc[13], acc[14], acc[15]);
        }
        __syncthreads();                             // bar1

        // stage 2: (o = tt&15, g = tt>>4) sums 2 writers each
        {
            const int o = tt & 15, g = tt >> 4;
            parth[(g << 4) + o] =
                redh[((g << 1) + 0) * 20 + o] + redh[((g << 1) + 1) * 20 + o];
        }
        __syncthreads();                             // bar2

        // stage 3: 16 threads per half finish s_o
        if (tt < 16) {
            float s = 0.f;
            #pragma unroll
            for (int g = 0; g < 16; ++g) s += parth[(g << 4) + tt];
            const float Z = (round == 0)
                ? (float)R_ROUTES
                : (sredh[0] + sredh[1] + sredh[2] + sredh[3]);
            svh[tt] = s / Z;
        }
        __syncthreads();                             // bar3

        // squash factor (same-address LDS reads broadcast: free)
        float svr[16];
        float sn = 0.f;
        #pragma unroll
        for (int o = 0; o < 16; ++o) { svr[o] = svh[o]; sn = fmaf(svr[o], svr[o], sn); }
        const float factor = sn / ((1.0f + sn) * sqrtf(sn));

        if (round == NUM_ROUNDS - 1) {
            if (tt < 16)
                out[((size_t)n * BATCH + 2 * bp + half) * COUT + tt] = factor * svr[tt];
        } else {
            // logit update: re-read owned rows (conflict-free b128)
            #pragma unroll
            for (int k = 0; k < 5; ++k) {
                if (k < nr) {
                    const int r = tt + (k << 8);
                    const uint4 a = *(const uint4*)(pb + sunit(r, 0) * 4);
                    const uint4 c = *(const uint4*)(pb + sunit(r, 1) * 4);
                    float d;
                    d = svr[0] * bf_lo(a.x);
                    d = fmaf(svr[1],  bf_hi(a.x), d);
                    d = fmaf(svr[2],  bf_lo(a.y), d);
                    d = fmaf(svr[3],  bf_hi(a.y), d);
                    d = fmaf(svr[4],  bf_lo(a.z), d);
                    d = fmaf(svr[5],  bf_hi(a.z), d);
                    d = fmaf(svr[6],  bf_lo(a.w), d);
                    d = fmaf(svr[7],  bf_hi(a.w), d);
                    d = fmaf(svr[8],  bf_lo(c.x), d);
                    d = fmaf(svr[9],  bf_hi(c.x), d);
                    d = fmaf(svr[10], bf_lo(c.y), d);
                    d = fmaf(svr[11], bf_hi(c.y), d);
                    d = fmaf(svr[12], bf_lo(c.z), d);
                    d = fmaf(svr[13], bf_hi(c.z), d);
                    d = fmaf(svr[14], bf_lo(c.w), d);
                    d = fmaf(svr[15], bf_hi(c.w), d);
                    bl[k] = fmaf(factor, d, bl[k]);
                }
            }
            // no barrier: next round's cross-thread LDS writes are ordered
            // by bar1..bar3 against this round's reads.
        }
    }
}

extern "C" void kernel_launch(void* const* d_in, const int* in_sizes, int n_in,
                              void* d_out, int out_size, void* d_ws, size_t ws_size,
                              hipStream_t stream) {
    const float* x = (const float*)d_in[0];   // [512, 1152, 8] fp32
    const float* W = (const float*)d_in[1];   // [10, 1152, 8, 16] fp32
    float* out = (float*)d_out;               // [10, 512, 1, 1, 16] fp32

    dim3 grid(NCAPS * (BATCH / 2));           // 2560 blocks, n-major
    dim3 block(512);
    capsule_routing_v7<<<grid, block, 0, stream>>>(x, W, out);
}

// Round 9
// 148.260 us; speedup vs baseline: 12.9662x; 1.0909x over previous
//
#include <hip/hip_runtime.h>
#include <math.h>

#define R_ROUTES 1152
#define CIN 8
#define COUT 16
#define BATCH 512
#define NCAPS 10
#define NUM_ROUNDS 3

typedef __fp16 h2 __attribute__((ext_vector_type(2)));
union U32H2 { unsigned int u; h2 h; };

__device__ __forceinline__ unsigned int pkrtz(float lo, float hi) {
    U32H2 v; v.h = __builtin_amdgcn_cvt_pkrtz(lo, hi);   // v_cvt_pkrtz_f16_f32
    return v.u;
}
__device__ __forceinline__ h2 as_h2(unsigned int u) { U32H2 v; v.u = u; return v.h; }
__device__ __forceinline__ float f_lo(unsigned int u) { return (float)as_h2(u).x; }
__device__ __forceinline__ float f_hi(unsigned int u) { return (float)as_h2(u).y; }
__device__ __forceinline__ float dot2(unsigned int p, unsigned int s, float c) {
    return __builtin_amdgcn_fdot2(as_h2(p), as_h2(s), c, false);  // v_dot2_f32_f16
}

// Swizzled 16-B-unit index for (row r, half h): bijection within each 128-B
// group, spreads consecutive-r b128 reads over all 8 bank groups (R5-verified).
__device__ __forceinline__ int sunit(int r, int h) {
    return (2 * r + h) ^ ((r >> 2) & 7);
}

// 512 threads per (n, b-pair): one W[n] row load serves both batches.
// Priors stored as PACKED F16 in LDS (same 32 B/row layout as bf16 version,
// better precision, 1-instr pack). Phase B: 3 fused passes -- pass p>0 does
// {logit update (8x v_dot2_f32_f16) + exp + weighted accumulate} in ONE pbuf
// read per row. LDS 81,408 B -> 2 blocks/CU = 16 waves/CU.
extern "C" __global__ void __launch_bounds__(512, 4)
capsule_routing_v8(const float* __restrict__ x,
                   const float* __restrict__ W,
                   float* __restrict__ out)
{
    __shared__ unsigned int pbuf[2 * R_ROUTES * 8];  // 73728 B f16 priors (swizzled)
    __shared__ float red[2 * 32 * 20];               // 5120 B writer scratch
    __shared__ float sred[2 * 4];                    // per-wave exp sums
    __shared__ float sv[2 * 16];                     // s vectors

    const int blk = blockIdx.x;                      // n-major: W[n] L2-resident
    const int n = blk >> 8;
    const int bp = blk & 255;
    const int t = threadIdx.x;

    const float* __restrict__ x0 = x + (size_t)(2 * bp) * (R_ROUTES * CIN);
    const float* __restrict__ x1 = x0 + R_ROUTES * CIN;
    const float* __restrict__ Wn = W + (size_t)n * (R_ROUTES * CIN * COUT);

    // ---------------- Phase A: one W row -> f16 priors for BOTH batches
    {
        const int q = t >> 2;                        // 0..127
        const int oq = t & 3;                        // column quad
        const int subw = (oq & 1) * 2;               // u32 sub-offset in 16-B unit
        const int hq = oq >> 1;                      // which 16-B half

        #pragma unroll 1                             // unroll>1 spills (R6: 87 MB scratch)
        for (int it = 0; it < 9; ++it) {
            const int r = it * 128 + q;
            const float4* __restrict__ wp = (const float4*)(Wn + (size_t)r * 128) + oq;
            float4 wv[8];
            #pragma unroll
            for (int i = 0; i < 8; ++i) wv[i] = wp[i * 4];
            const float4 xa0 = *(const float4*)(x0 + r * 8);
            const float4 xa1 = *(const float4*)(x0 + r * 8 + 4);
            const float4 xb0 = *(const float4*)(x1 + r * 8);
            const float4 xb1 = *(const float4*)(x1 + r * 8 + 4);

            {   // batch 0
                const float xs[8] = {xa0.x, xa0.y, xa0.z, xa0.w,
                                     xa1.x, xa1.y, xa1.z, xa1.w};
                float a0 = 0.f, a1 = 0.f, a2 = 0.f, a3 = 0.f;
                #pragma unroll
                for (int i = 0; i < 8; ++i) {
                    a0 = fmaf(xs[i], wv[i].x, a0);
                    a1 = fmaf(xs[i], wv[i].y, a1);
                    a2 = fmaf(xs[i], wv[i].z, a2);
                    a3 = fmaf(xs[i], wv[i].w, a3);
                }
                uint2 u; u.x = pkrtz(a0, a1); u.y = pkrtz(a2, a3);
                *(uint2*)(pbuf + sunit(r, hq) * 4 + subw) = u;
            }
            {   // batch 1
                const float xs[8] = {xb0.x, xb0.y, xb0.z, xb0.w,
                                     xb1.x, xb1.y, xb1.z, xb1.w};
                float a0 = 0.f, a1 = 0.f, a2 = 0.f, a3 = 0.f;
                #pragma unroll
                for (int i = 0; i < 8; ++i) {
                    a0 = fmaf(xs[i], wv[i].x, a0);
                    a1 = fmaf(xs[i], wv[i].y, a1);
                    a2 = fmaf(xs[i], wv[i].z, a2);
                    a3 = fmaf(xs[i], wv[i].w, a3);
                }
                uint2 u; u.x = pkrtz(a0, a1); u.y = pkrtz(a2, a3);
                *(uint2*)(pbuf + R_ROUTES * 8 + sunit(r, hq) * 4 + subw) = u;
            }
        }
    }
    __syncthreads();   // Phase A writers -> Phase B owners

    // ---------------- Phase B: 3 fused passes, two 256-thread halves
    const int half = t >> 8;                         // 0 or 1 (wave-aligned)
    const int tt = t & 255;
    unsigned int* __restrict__ pb = pbuf + half * (R_ROUTES * 8);
    float* __restrict__ redh = red + half * (32 * 20);
    float* __restrict__ sredh = sred + half * 4;
    float* __restrict__ svh = sv + half * 16;

    const int nr = (tt < 128) ? 5 : 4;               // wave-uniform
    float bl[5] = {0.f, 0.f, 0.f, 0.f, 0.f};
    float factor = 0.f;                              // squash factor of prev pass

    for (int pass = 0; pass < NUM_ROUNDS; ++pass) {
        float acc[16];
        #pragma unroll
        for (int o = 0; o < 16; ++o) acc[o] = 0.f;
        float es = 0.f;

        if (pass == 0) {
            // uniform softmax: acc = sum of own rows
            #pragma unroll
            for (int k = 0; k < 5; ++k) {
                if (k < nr) {
                    const int r = tt + (k << 8);
                    const uint4 a = *(const uint4*)(pb + sunit(r, 0) * 4);
                    const uint4 c = *(const uint4*)(pb + sunit(r, 1) * 4);
                    acc[0]  += f_lo(a.x); acc[1]  += f_hi(a.x);
                    acc[2]  += f_lo(a.y); acc[3]  += f_hi(a.y);
                    acc[4]  += f_lo(a.z); acc[5]  += f_hi(a.z);
                    acc[6]  += f_lo(a.w); acc[7]  += f_hi(a.w);
                    acc[8]  += f_lo(c.x); acc[9]  += f_hi(c.x);
                    acc[10] += f_lo(c.y); acc[11] += f_hi(c.y);
                    acc[12] += f_lo(c.z); acc[13] += f_hi(c.z);
                    acc[14] += f_lo(c.w); acc[15] += f_hi(c.w);
                }
            }
        } else {
            // fused: logit update (dot2) + exp + weighted accumulate, one read
            unsigned int svp[8];
            #pragma unroll
            for (int j = 0; j < 8; ++j)
                svp[j] = pkrtz(svh[2 * j], svh[2 * j + 1]);  // broadcast reads
            #pragma unroll
            for (int k = 0; k < 5; ++k) {
                if (k < nr) {
                    const int r = tt + (k << 8);
                    const uint4 a = *(const uint4*)(pb + sunit(r, 0) * 4);
                    const uint4 c = *(const uint4*)(pb + sunit(r, 1) * 4);
                    float d = 0.f;
                    d = dot2(a.x, svp[0], d);
                    d = dot2(a.y, svp[1], d);
                    d = dot2(a.z, svp[2], d);
                    d = dot2(a.w, svp[3], d);
                    d = dot2(c.x, svp[4], d);
                    d = dot2(c.y, svp[5], d);
                    d = dot2(c.z, svp[6], d);
                    d = dot2(c.w, svp[7], d);
                    bl[k] = fmaf(factor, d, bl[k]);
                    const float e = __expf(bl[k]);
                    es += e;
                    acc[0]  = fmaf(e, f_lo(a.x), acc[0]);
                    acc[1]  = fmaf(e, f_hi(a.x), acc[1]);
                    acc[2]  = fmaf(e, f_lo(a.y), acc[2]);
                    acc[3]  = fmaf(e, f_hi(a.y), acc[3]);
                    acc[4]  = fmaf(e, f_lo(a.z), acc[4]);
                    acc[5]  = fmaf(e, f_hi(a.z), acc[5]);
                    acc[6]  = fmaf(e, f_lo(a.w), acc[6]);
                    acc[7]  = fmaf(e, f_hi(a.w), acc[7]);
                    acc[8]  = fmaf(e, f_lo(c.x), acc[8]);
                    acc[9]  = fmaf(e, f_hi(c.x), acc[9]);
                    acc[10] = fmaf(e, f_lo(c.y), acc[10]);
                    acc[11] = fmaf(e, f_hi(c.y), acc[11]);
                    acc[12] = fmaf(e, f_lo(c.z), acc[12]);
                    acc[13] = fmaf(e, f_hi(c.z), acc[13]);
                    acc[14] = fmaf(e, f_lo(c.w), acc[14]);
                    acc[15] = fmaf(e, f_hi(c.w), acc[15]);
                }
            }
            // wave-sum of exp weights -> sredh (read at merged stage after bar1)
            #pragma unroll
            for (int off = 32; off > 0; off >>= 1) es += __shfl_xor(es, off, 64);
            if ((t & 63) == 0) sredh[tt >> 6] = es;
        }

        // 8-lane shuffle pre-reduce -> 32 LDS writers per half
        #pragma unroll
        for (int o = 0; o < 16; ++o) {
            acc[o] += __shfl_xor(acc[o], 1, 64);
            acc[o] += __shfl_xor(acc[o], 2, 64);
            acc[o] += __shfl_xor(acc[o], 4, 64);
        }
        if ((tt & 7) == 0) {
            float* dst = redh + (tt >> 3) * 20;      // 80-B stride: conflict-free b128
            *(float4*)(dst + 0)  = make_float4(acc[0],  acc[1],  acc[2],  acc[3]);
            *(float4*)(dst + 4)  = make_float4(acc[4],  acc[5],  acc[6],  acc[7]);
            *(float4*)(dst + 8)  = make_float4(acc[8],  acc[9],  acc[10], acc[11]);
            *(float4*)(dst + 12) = make_float4(acc[12], acc[13], acc[14], acc[15]);
        }
        __syncthreads();                             // bar1

        // merged stage: 16 threads per half sum all 32 writers + normalize
        if (tt < 16) {
            float s = 0.f;
            #pragma unroll
            for (int w = 0; w < 32; ++w) s += redh[w * 20 + tt];
            const float Z = (pass == 0)
                ? (float)R_ROUTES
                : (sredh[0] + sredh[1] + sredh[2] + sredh[3]);
            svh[tt] = s / Z;
        }
        __syncthreads();                             // bar2
        // (next pass's redh/sredh/svh writes all occur after this barrier,
        //  and this pass's reads complete before it -> no WAR hazard)

        // squash factor (same-address LDS broadcasts: free)
        float sn = 0.f;
        #pragma unroll
        for (int o = 0; o < 16; ++o) { const float s = svh[o]; sn = fmaf(s, s, sn); }
        factor = sn / ((1.0f + sn) * sqrtf(sn));
    }

    if (tt < 16)
        out[((size_t)n * BATCH + 2 * bp + half) * COUT + tt] = factor * svh[tt];
}

extern "C" void kernel_launch(void* const* d_in, const int* in_sizes, int n_in,
                              void* d_out, int out_size, void* d_ws, size_t ws_size,
                              hipStream_t stream) {
    const float* x = (const float*)d_in[0];   // [512, 1152, 8] fp32
    const float* W = (const float*)d_in[1];   // [10, 1152, 8, 16] fp32
    float* out = (float*)d_out;               // [10, 512, 1, 1, 16] fp32

    dim3 grid(NCAPS * (BATCH / 2));           // 2560 blocks, n-major
    dim3 block(512);
    capsule_routing_v8<<<grid, block, 0, stream>>>(x, W, out);
}

// Round 10
// 136.352 us; speedup vs baseline: 14.0987x; 1.0873x over previous
//
#include <hip/hip_runtime.h>
#include <math.h>

#define R_ROUTES 1152
#define CIN 8
#define COUT 16
#define BATCH 512
#define NCAPS 10
#define NUM_ROUNDS 3

typedef __fp16 h2 __attribute__((ext_vector_type(2)));
union U32H2 { unsigned int u; h2 h; };

__device__ __forceinline__ unsigned int pkrtz(float lo, float hi) {
    U32H2 v; v.h = __builtin_amdgcn_cvt_pkrtz(lo, hi);   // v_cvt_pkrtz_f16_f32
    return v.u;
}
__device__ __forceinline__ h2 as_h2(unsigned int u) { U32H2 v; v.u = u; return v.h; }
__device__ __forceinline__ float f_lo(unsigned int u) { return (float)as_h2(u).x; }
__device__ __forceinline__ float f_hi(unsigned int u) { return (float)as_h2(u).y; }
__device__ __forceinline__ float dot2(unsigned int p, unsigned int s, float c) {
    return __builtin_amdgcn_fdot2(as_h2(p), as_h2(s), c, false);  // v_dot2_f32_f16
}

// Swizzled 16-B-unit index for (row r, half h): bijection within each 128-B
// group, spreads consecutive-r b128 reads over all 8 bank groups (R5-verified).
__device__ __forceinline__ int sunit(int r, int h) {
    return (2 * r + h) ^ ((r >> 2) & 7);
}

// ---------------- Kernel 1: W fp32 [n][r][i][o] -> f16-pair Wp [n][r][o][i/2]
// Wp row (one r) = 16 o * 4 u32 = 256 B. 2,949,120 B total in d_ws (L2-resident).
extern "C" __global__ void __launch_bounds__(256)
pack_w(const float* __restrict__ W, unsigned int* __restrict__ Wp)
{
    const int tau = blockIdx.x * 256 + threadIdx.x;    // one thread per (n,r,o)
    const int o = tau & 15;
    const int nr = tau >> 4;                           // n*1152 + r
    const float* __restrict__ src = W + (size_t)nr * 128 + o;
    uint4 u;
    u.x = pkrtz(src[0],  src[16]);    // (i0,i1)
    u.y = pkrtz(src[32], src[48]);    // (i2,i3)
    u.z = pkrtz(src[64], src[80]);    // (i4,i5)
    u.w = pkrtz(src[96], src[112]);   // (i6,i7)
    *(uint4*)(Wp + (size_t)tau * 4) = u;
}

// ---------------- Main: 512 threads per (n, b-pair), f16 everywhere.
// Phase A: quad (4 lanes) per row; lane oq owns o in {oq, oq+4, oq+8, oq+12};
// priors = 4 dot2 per o from Wp; ALSO accumulates pass-0 column sums (f32).
// Columns live in permuted order P[k] = (k>>2) + ((k&3)<<2) end-to-end;
// un-permuted only at the final store. Phase B: 2 fused passes (pass 0 was
// absorbed into Phase A). LDS ~80 KB -> 2 blocks/CU = 16 waves/CU.
extern "C" __global__ void __launch_bounds__(512, 4)
capsule_routing_v9(const float* __restrict__ x,
                   const unsigned int* __restrict__ Wp,
                   float* __restrict__ out)
{
    __shared__ unsigned int pbuf[2 * R_ROUTES * 8];  // 73728 B f16 priors (swizzled)
    __shared__ float wred[16 * 16];                  // 1024 B: (wave*2+b)*16 + k
    __shared__ float red[2 * 32 * 20];               // 5120 B pass-reduction scratch
    __shared__ float sred[2 * 4];                    // per-wave exp sums
    __shared__ float sv[2 * 16];                     // s vectors (permuted order)

    const int blk = blockIdx.x;                      // n-major: Wp[n] L2-resident
    const int n = blk >> 8;
    const int bp = blk & 255;
    const int t = threadIdx.x;

    const float* __restrict__ x0 = x + (size_t)(2 * bp) * (R_ROUTES * CIN);
    const float* __restrict__ x1 = x0 + R_ROUTES * CIN;
    const unsigned int* __restrict__ Wn = Wp + (size_t)n * (R_ROUTES * 64);

    // ---------------- Phase A: priors (dot2) + pass-0 colsums
    float cs[2][4] = {{0.f, 0.f, 0.f, 0.f}, {0.f, 0.f, 0.f, 0.f}};
    {
        const int q = t >> 2;                        // 0..127
        const int oq = t & 3;
        const int subw = (oq & 1) * 2;               // u32 sub-offset in 16-B unit
        const int hq = oq >> 1;                      // which 16-B half

        #pragma unroll 1                             // unroll>1 spills (R6 lesson)
        for (int it = 0; it < 9; ++it) {
            const int r = it * 128 + q;
            const unsigned int* __restrict__ wb = Wn + (size_t)r * 64;
            const uint4 w0 = *(const uint4*)(wb + (oq + 0) * 4);   // o = oq
            const uint4 w1 = *(const uint4*)(wb + (oq + 4) * 4);   // o = oq+4
            const uint4 w2 = *(const uint4*)(wb + (oq + 8) * 4);   // o = oq+8
            const uint4 w3 = *(const uint4*)(wb + (oq + 12) * 4);  // o = oq+12
            const float4 xa0 = *(const float4*)(x0 + r * 8);
            const float4 xa1 = *(const float4*)(x0 + r * 8 + 4);
            const float4 xb0 = *(const float4*)(x1 + r * 8);
            const float4 xb1 = *(const float4*)(x1 + r * 8 + 4);

            {   // batch 0
                const unsigned int xp0 = pkrtz(xa0.x, xa0.y), xp1 = pkrtz(xa0.z, xa0.w);
                const unsigned int xp2 = pkrtz(xa1.x, xa1.y), xp3 = pkrtz(xa1.z, xa1.w);
                const float p0 = dot2(w0.w, xp3, dot2(w0.z, xp2, dot2(w0.y, xp1, dot2(w0.x, xp0, 0.f))));
                const float p1 = dot2(w1.w, xp3, dot2(w1.z, xp2, dot2(w1.y, xp1, dot2(w1.x, xp0, 0.f))));
                const float p2 = dot2(w2.w, xp3, dot2(w2.z, xp2, dot2(w2.y, xp1, dot2(w2.x, xp0, 0.f))));
                const float p3 = dot2(w3.w, xp3, dot2(w3.z, xp2, dot2(w3.y, xp1, dot2(w3.x, xp0, 0.f))));
                cs[0][0] += p0; cs[0][1] += p1; cs[0][2] += p2; cs[0][3] += p3;
                uint2 u; u.x = pkrtz(p0, p1); u.y = pkrtz(p2, p3);  // slots 2oq, 2oq+1
                *(uint2*)(pbuf + sunit(r, hq) * 4 + subw) = u;
            }
            {   // batch 1
                const unsigned int xp0 = pkrtz(xb0.x, xb0.y), xp1 = pkrtz(xb0.z, xb0.w);
                const unsigned int xp2 = pkrtz(xb1.x, xb1.y), xp3 = pkrtz(xb1.z, xb1.w);
                const float p0 = dot2(w0.w, xp3, dot2(w0.z, xp2, dot2(w0.y, xp1, dot2(w0.x, xp0, 0.f))));
                const float p1 = dot2(w1.w, xp3, dot2(w1.z, xp2, dot2(w1.y, xp1, dot2(w1.x, xp0, 0.f))));
                const float p2 = dot2(w2.w, xp3, dot2(w2.z, xp2, dot2(w2.y, xp1, dot2(w2.x, xp0, 0.f))));
                const float p3 = dot2(w3.w, xp3, dot2(w3.z, xp2, dot2(w3.y, xp1, dot2(w3.x, xp0, 0.f))));
                cs[1][0] += p0; cs[1][1] += p1; cs[1][2] += p2; cs[1][3] += p3;
                uint2 u; u.x = pkrtz(p0, p1); u.y = pkrtz(p2, p3);
                *(uint2*)(pbuf + R_ROUTES * 8 + sunit(r, hq) * 4 + subw) = u;
            }
        }

        // pass-0 reduce: butterfly over same-oq lanes (masks 4..32)
        #pragma unroll
        for (int mask = 4; mask <= 32; mask <<= 1) {
            #pragma unroll
            for (int b = 0; b < 2; ++b)
                #pragma unroll
                for (int j = 0; j < 4; ++j)
                    cs[b][j] += __shfl_xor(cs[b][j], mask, 64);
        }
        if ((t & 63) < 4) {                          // lane oq of each wave writes
            const int w = t >> 6;
            *(float4*)(wred + (w * 2 + 0) * 16 + 4 * oq) =
                make_float4(cs[0][0], cs[0][1], cs[0][2], cs[0][3]);
            *(float4*)(wred + (w * 2 + 1) * 16 + 4 * oq) =
                make_float4(cs[1][0], cs[1][1], cs[1][2], cs[1][3]);
        }
    }
    __syncthreads();                                 // barA1 (also pbuf ready)

    // ---------------- Phase B setup
    const int half = t >> 8;
    const int tt = t & 255;
    unsigned int* __restrict__ pb = pbuf + half * (R_ROUTES * 8);
    float* __restrict__ redh = red + half * (32 * 20);
    float* __restrict__ sredh = sred + half * 4;
    float* __restrict__ svh = sv + half * 16;        // permuted order: svh[k] = v[P[k]]

    if (tt < 16) {
        float s = 0.f;
        #pragma unroll
        for (int w = 0; w < 8; ++w) s += wred[(w * 2 + half) * 16 + tt];
        svh[tt] = s * (1.0f / (float)R_ROUTES);
    }
    __syncthreads();                                 // barA2

    float sn = 0.f;
    #pragma unroll
    for (int o = 0; o < 16; ++o) { const float s = svh[o]; sn = fmaf(s, s, sn); }
    float factor = sn / ((1.0f + sn) * sqrtf(sn));

    const int nr = (tt < 128) ? 5 : 4;               // wave-uniform
    float bl[5] = {0.f, 0.f, 0.f, 0.f, 0.f};

    // ---------------- passes 1..2: fused logit-update + exp + weighted sum
    #pragma unroll 1
    for (int pass = 1; pass < NUM_ROUNDS; ++pass) {
        unsigned int svp[8];
        #pragma unroll
        for (int s = 0; s < 8; ++s)
            svp[s] = pkrtz(svh[2 * s], svh[2 * s + 1]);   // pairing matches slots
        float acc[16];
        #pragma unroll
        for (int o = 0; o < 16; ++o) acc[o] = 0.f;
        float es = 0.f;

        #pragma unroll
        for (int k = 0; k < 5; ++k) {
            if (k < nr) {
                const int r = tt + (k << 8);
                const uint4 a = *(const uint4*)(pb + sunit(r, 0) * 4);
                const uint4 c = *(const uint4*)(pb + sunit(r, 1) * 4);
                float d = 0.f;
                d = dot2(a.x, svp[0], d);
                d = dot2(a.y, svp[1], d);
                d = dot2(a.z, svp[2], d);
                d = dot2(a.w, svp[3], d);
                d = dot2(c.x, svp[4], d);
                d = dot2(c.y, svp[5], d);
                d = dot2(c.z, svp[6], d);
                d = dot2(c.w, svp[7], d);
                bl[k] = fmaf(factor, d, bl[k]);
                const float e = __expf(bl[k]);
                es += e;
                acc[0]  = fmaf(e, f_lo(a.x), acc[0]);
                acc[1]  = fmaf(e, f_hi(a.x), acc[1]);
                acc[2]  = fmaf(e, f_lo(a.y), acc[2]);
                acc[3]  = fmaf(e, f_hi(a.y), acc[3]);
                acc[4]  = fmaf(e, f_lo(a.z), acc[4]);
                acc[5]  = fmaf(e, f_hi(a.z), acc[5]);
                acc[6]  = fmaf(e, f_lo(a.w), acc[6]);
                acc[7]  = fmaf(e, f_hi(a.w), acc[7]);
                acc[8]  = fmaf(e, f_lo(c.x), acc[8]);
                acc[9]  = fmaf(e, f_hi(c.x), acc[9]);
                acc[10] = fmaf(e, f_lo(c.y), acc[10]);
                acc[11] = fmaf(e, f_hi(c.y), acc[11]);
                acc[12] = fmaf(e, f_lo(c.z), acc[12]);
                acc[13] = fmaf(e, f_hi(c.z), acc[13]);
                acc[14] = fmaf(e, f_lo(c.w), acc[14]);
                acc[15] = fmaf(e, f_hi(c.w), acc[15]);
            }
        }
        #pragma unroll
        for (int off = 32; off > 0; off >>= 1) es += __shfl_xor(es, off, 64);
        if ((t & 63) == 0) sredh[tt >> 6] = es;

        // 8-lane shuffle pre-reduce -> 32 LDS writers per half
        #pragma unroll
        for (int o = 0; o < 16; ++o) {
            acc[o] += __shfl_xor(acc[o], 1, 64);
            acc[o] += __shfl_xor(acc[o], 2, 64);
            acc[o] += __shfl_xor(acc[o], 4, 64);
        }
        if ((tt & 7) == 0) {
            float* dst = redh + (tt >> 3) * 20;      // 80-B stride: conflict-free b128
            *(float4*)(dst + 0)  = make_float4(acc[0],  acc[1],  acc[2],  acc[3]);
            *(float4*)(dst + 4)  = make_float4(acc[4],  acc[5],  acc[6],  acc[7]);
            *(float4*)(dst + 8)  = make_float4(acc[8],  acc[9],  acc[10], acc[11]);
            *(float4*)(dst + 12) = make_float4(acc[12], acc[13], acc[14], acc[15]);
        }
        __syncthreads();                             // bar1

        if (tt < 16) {
            float s = 0.f;
            #pragma unroll
            for (int w = 0; w < 32; ++w) s += redh[w * 20 + tt];
            const float Z = sredh[0] + sredh[1] + sredh[2] + sredh[3];
            svh[tt] = s / Z;
        }
        __syncthreads();                             // bar2

        sn = 0.f;
        #pragma unroll
        for (int o = 0; o < 16; ++o) { const float s = svh[o]; sn = fmaf(s, s, sn); }
        factor = sn / ((1.0f + sn) * sqrtf(sn));
    }

    if (tt < 16) {
        const int o = (tt >> 2) + ((tt & 3) << 2);   // un-permute P[tt]
        out[((size_t)n * BATCH + 2 * bp + half) * COUT + o] = factor * svh[tt];
    }
}

extern "C" void kernel_launch(void* const* d_in, const int* in_sizes, int n_in,
                              void* d_out, int out_size, void* d_ws, size_t ws_size,
                              hipStream_t stream) {
    const float* x = (const float*)d_in[0];   // [512, 1152, 8] fp32
    const float* W = (const float*)d_in[1];   // [10, 1152, 8, 16] fp32
    float* out = (float*)d_out;               // [10, 512, 1, 1, 16] fp32
    unsigned int* Wp = (unsigned int*)d_ws;   // 2,949,120 B f16-packed W

    pack_w<<<dim3(NCAPS * R_ROUTES * COUT / 256), dim3(256), 0, stream>>>(W, Wp);
    capsule_routing_v9<<<dim3(NCAPS * (BATCH / 2)), dim3(512), 0, stream>>>(x, Wp, out);
}